// Round 6
// baseline (110.101 us; speedup 1.0000x reference)
//
#include <hip/hip_runtime.h>

#define TLEN 512
#define LOG2E 1.44269504088896340736f

#if __has_builtin(__builtin_amdgcn_exp2f)
#define EXP2F(x) __builtin_amdgcn_exp2f(x)
#else
#define EXP2F(x) __exp2f(x)
#endif
#if __has_builtin(__builtin_amdgcn_rcpf)
#define RCPF(x) __builtin_amdgcn_rcpf(x)
#else
#define RCPF(x) (1.0f / (x))
#endif

// ds_swizzle BitMode xor (epilogue MLP head only, off the hot loop)
#define SWZ(v, xm) __int_as_float(__builtin_amdgcn_ds_swizzle(__float_as_int(v), (((xm) << 10) | 0x1F)))
// Generic DPP: dst = src[permuted lane], all lanes valid
#define DPPF(v, ctrl) __int_as_float(__builtin_amdgcn_update_dpp(__float_as_int(v), __float_as_int(v), (ctrl), 0xF, 0xF, false))
// quad_perm broadcast of quad-lane k
#define QB(v, k) DPPF(v, 0x55 * (k))
// Direction-free lane exchanges within a row of 16 (verified rounds 1-2, absmax 0):
#define XOR3(v)  DPPF(v, 0x1B)   // quad_perm [3,2,1,0]
#define XOR7(v)  DPPF(v, 0x141)  // ROW_HALF_MIRROR
#define XOR8(v)  DPPF(v, 0x128)  // ROW_ROR:8

// counted vmcnt wait; "memory" clobber orders all memory ops (ds_read, DMA,
// compiler weight loads) across it -> vmcnt arithmetic inside the loop is
// exact and LDS reads can't hoist above the wait. No register hazard exists:
// the DMA has no destination register.
#define WAITVM(N) asm volatile("s_waitcnt vmcnt(" #N ")" ::: "memory")

typedef const __attribute__((address_space(1))) unsigned int gu32;
typedef __attribute__((address_space(3))) unsigned int lu32;

__global__ __launch_bounds__(256, 1) void lstm_mlp_kernel(
    const float* __restrict__ x,   // [B,512,16]
    const float* __restrict__ Wk,  // [16,16]
    const float* __restrict__ Wr,  // [4,16]
    const float* __restrict__ bg,  // [16]
    const float* __restrict__ W1,  // [4,64]
    const float* __restrict__ b1,  // [64]
    const float* __restrict__ W2,  // [64,5]
    const float* __restrict__ b2,  // [5]
    float* __restrict__ out,       // [B,5]
    int B)
{
    // per-wave private LDS ring: [wave][slot][dt*16 + chunk*4 + seq] float4
    // slot = 4 timesteps (1KB). 4 waves x 4KB = 16KB. No cross-wave sharing,
    // no barriers.
    __shared__ float4 lds[4][4][64];

    const int tidx = threadIdx.x;
    const int w   = tidx >> 6;         // wave in block
    const int L   = tidx & 63;         // lane
    const int sl  = (tidx >> 4) & 3;   // compute: seq-local within wave
    const int i16 = tidx & 15;
    const int j   = i16 >> 2;          // hidden unit owned by this quad
    const int q   = i16 & 3;           // gate type: 0=i, 1=f, 2=g(tanh), 3=o
    const int gate = q * 4 + j;        // column in gates[16] (Keras i,f,g,o)

    // activation pre-scale folded into weights (verified rounds 1-2, absmax 0)
    const bool is_g = (q == 2);
    const float k1 = is_g ? (-2.0f * LOG2E) : (-LOG2E);
    const float m1c = is_g ? (-4.0f * LOG2E) : 1.0f;
    const float m0c = is_g ? (2.0f * LOG2E) : 0.0f;

    float wk[16];
#pragma unroll
    for (int f = 0; f < 16; ++f) wk[f] = k1 * Wk[f * 16 + gate];
    const float wr0 = k1 * Wr[(j ^ 0) * 16 + gate];
    const float wr1 = k1 * Wr[(j ^ 1) * 16 + gate];
    const float wr2 = k1 * Wr[(j ^ 2) * 16 + gate];
    const float wr3 = k1 * Wr[(j ^ 3) * 16 + gate];
    const float biasS = k1 * bg[gate];

    // DMA lane mapping: lane L fetches 16B = (seq dseq, timestep t0+dtl, chunk)
    // LDS dest is linear base + L*16 -> layout [dt][chunk][seq] float4, which
    // makes the compute-side broadcast reads bank-disjoint across seq groups.
    const int dseq = L & 3;
    const int dtl  = L >> 4;
    const int chnk = (L >> 2) & 3;
    const float* xb = x + ((size_t)(blockIdx.x * 16 + w * 4 + dseq) * TLEN + dtl) * 16 + chnk * 4;

#define DMA(SLOT, T0) \
    __builtin_amdgcn_global_load_lds((gu32*)(const void*)(xb + (size_t)(T0) * 16), \
                                     (lu32*)(void*)(&lds[w][SLOT][0]), 16, 0, 0)

    const float4* __restrict__ lw = &lds[w][0][0];   // 256 float4 per wave

    float cs = 0.0f, h = 0.0f;   // cs = -2*log2e * c

#define DOT4S(v, w0_, w1_, w2_, w3_, seed) \
    fmaf((v).x, (w0_), fmaf((v).y, (w1_), fmaf((v).z, (w2_), fmaf((v).w, (w3_), (seed)))))

#define RD_DOT(BASE, OFF, DST) { \
    float4 ra_ = (BASE)[(OFF) + sl]; \
    float4 rb_ = (BASE)[(OFF) + sl + 4]; \
    float4 rc_ = (BASE)[(OFF) + sl + 8]; \
    float4 rd_ = (BASE)[(OFF) + sl + 12]; \
    DST = (DOT4S(ra_, wk[0], wk[1], wk[2], wk[3], biasS) + \
           DOT4S(rb_, wk[4], wk[5], wk[6], wk[7], 0.0f)) + \
          (DOT4S(rc_, wk[8], wk[9], wk[10], wk[11], 0.0f) + \
           DOT4S(rd_, wk[12], wk[13], wk[14], wk[15], 0.0f)); }

#define STEP(XD) { \
    float h1_ = XOR7(XOR3(h));   /* h[j^1] */ \
    float h2_ = XOR8(h);         /* h[j^2] */ \
    float h3_ = XOR8(h1_);       /* h[j^3] */ \
    float pre = fmaf(h, wr0, (XD)); \
    pre = fmaf(h2_, wr2, pre); \
    pre = fmaf(h1_, wr1, pre); \
    pre = fmaf(h3_, wr3, pre); \
    float r_ = RCPF(1.0f + EXP2F(pre)); \
    float av = fmaf(m1c, r_, m0c); \
    float iv = QB(av, 0); \
    float fv = QB(av, 1); \
    float gv = QB(av, 2); \
    float ov = QB(av, 3); \
    cs = fmaf(fv, cs, iv * gv); \
    float th_ = fmaf(2.0f, RCPF(1.0f + EXP2F(cs)), -1.0f); \
    h = ov * th_; }

    // prologue: clean vmcnt baseline (weight loads fenced above by program
    // order + memory clobber), fill 4 ring slots (groups 0..3)
    WAITVM(0);
    DMA(0, 0);
    DMA(1, 4);
    DMA(2, 8);
    DMA(3, 12);
    WAITVM(3);                 // group 0 resident
    float xd;
    RD_DOT(lw, 0, xd);         // dot for step 0

    // main loop: iteration g consumes steps 4g..4g+3 (slot g&3), pre-dots the
    // next step across the boundary (slot (g+1)&3, resident via vmcnt(2)),
    // then refills slot g&3 with group g+4 (t0 clamped; the clamped refills of
    // the last iterations land in already-consumed slots -> harmless).
    // vmcnt invariant: 3 outstanding before wait, vmcnt(2) retires group g+1.
#pragma clang loop unroll(disable)
    for (int g = 0; g < 128; ++g) {
        WAITVM(2);
        const float4* lg  = lw + ((g & 3) << 6);
        const float4* lg1 = lw + (((g + 1) & 3) << 6);
        float xdn;
        RD_DOT(lg, 16, xdn); STEP(xd); xd = xdn;   // step 4g,   pre-dot 4g+1
        RD_DOT(lg, 32, xdn); STEP(xd); xd = xdn;   // step 4g+1, pre-dot 4g+2
        RD_DOT(lg, 48, xdn); STEP(xd); xd = xdn;   // step 4g+2, pre-dot 4g+3
        RD_DOT(lg1, 0, xdn); STEP(xd); xd = xdn;   // step 4g+3, pre-dot 4g+4
        int t0 = (g + 4) << 2;
        t0 = t0 > (TLEN - 4) ? (TLEN - 4) : t0;
        DMA(g & 3, t0);
    }
    // after iter 127: steps 0..511 all done; xd holds a discarded lookahead.
    WAITVM(0);   // drain trailing DMAs before epilogue

    // ---- MLP head (runs once; verified rounds 1-2) ----
    float hA = h;
    float hB = SWZ(h, 4), hC = SWZ(h, 8), hD = SWZ(h, 12);

    float p0 = 0.f, p1 = 0.f, p2 = 0.f, p3 = 0.f, p4 = 0.f;
#pragma unroll
    for (int r = 0; r < 4; ++r) {
        const int u = i16 * 4 + r;            // hidden unit of layer 1, 4 per lane
        float acc = b1[u];
        acc = fmaf(hA, W1[(j ^ 0) * 64 + u], acc);
        acc = fmaf(hB, W1[(j ^ 1) * 64 + u], acc);
        acc = fmaf(hC, W1[(j ^ 2) * 64 + u], acc);
        acc = fmaf(hD, W1[(j ^ 3) * 64 + u], acc);
        acc = fmaxf(acc, 0.0f);
        p0 = fmaf(acc, W2[u * 5 + 0], p0);
        p1 = fmaf(acc, W2[u * 5 + 1], p1);
        p2 = fmaf(acc, W2[u * 5 + 2], p2);
        p3 = fmaf(acc, W2[u * 5 + 3], p3);
        p4 = fmaf(acc, W2[u * 5 + 4], p4);
    }
    // butterfly all-reduce across the 16-lane group
    p0 += SWZ(p0, 1); p1 += SWZ(p1, 1); p2 += SWZ(p2, 1); p3 += SWZ(p3, 1); p4 += SWZ(p4, 1);
    p0 += SWZ(p0, 2); p1 += SWZ(p1, 2); p2 += SWZ(p2, 2); p3 += SWZ(p3, 2); p4 += SWZ(p4, 2);
    p0 += SWZ(p0, 4); p1 += SWZ(p1, 4); p2 += SWZ(p2, 4); p3 += SWZ(p3, 4); p4 += SWZ(p4, 4);
    p0 += SWZ(p0, 8); p1 += SWZ(p1, 8); p2 += SWZ(p2, 8); p3 += SWZ(p3, 8); p4 += SWZ(p4, 8);

    p0 += b2[0]; p1 += b2[1]; p2 += b2[2]; p3 += b2[3]; p4 += b2[4];

    float mx = fmaxf(fmaxf(fmaxf(p0, p1), fmaxf(p2, p3)), p4);
    float e0 = EXP2F((p0 - mx) * LOG2E);
    float e1 = EXP2F((p1 - mx) * LOG2E);
    float e2 = EXP2F((p2 - mx) * LOG2E);
    float e3 = EXP2F((p3 - mx) * LOG2E);
    float e4 = EXP2F((p4 - mx) * LOG2E);
    float s = ((e0 + e1) + (e2 + e3)) + e4;
    float rs = RCPF(s);

    if (i16 == 0) {
        const int seq = blockIdx.x * 16 + (tidx >> 4);
        float* op = out + (size_t)seq * 5;
        op[0] = e0 * rs; op[1] = e1 * rs; op[2] = e2 * rs;
        op[3] = e3 * rs; op[4] = e4 * rs;
    }
}

extern "C" void kernel_launch(void* const* d_in, const int* in_sizes, int n_in,
                              void* d_out, int out_size, void* d_ws, size_t ws_size,
                              hipStream_t stream) {
    const float* x  = (const float*)d_in[0];
    const float* Wk = (const float*)d_in[1];
    const float* Wr = (const float*)d_in[2];
    const float* bg = (const float*)d_in[3];
    const float* W1 = (const float*)d_in[4];
    const float* b1 = (const float*)d_in[5];
    const float* W2 = (const float*)d_in[6];
    const float* b2 = (const float*)d_in[7];
    float* out = (float*)d_out;

    const int B = in_sizes[0] / (TLEN * 16);   // 4096
    dim3 block(256);
    dim3 grid(B / 16);                         // 16 seqs per block (4 per wave)
    lstm_mlp_kernel<<<grid, block, 0, stream>>>(x, Wk, Wr, bg, W1, b1, W2, b2, out, B);
}

// Round 7
// 73.447 us; speedup vs baseline: 1.4991x; 1.4991x over previous
//
#include <hip/hip_runtime.h>

#define TLEN 512
#define LOG2E 1.44269504088896340736f

#if __has_builtin(__builtin_amdgcn_exp2f)
#define EXP2F(x) __builtin_amdgcn_exp2f(x)
#else
#define EXP2F(x) __exp2f(x)
#endif
#if __has_builtin(__builtin_amdgcn_rcpf)
#define RCPF(x) __builtin_amdgcn_rcpf(x)
#else
#define RCPF(x) (1.0f / (x))
#endif

// ds_swizzle BitMode xor (epilogue MLP head only, off the hot loop)
#define SWZ(v, xm) __int_as_float(__builtin_amdgcn_ds_swizzle(__float_as_int(v), (((xm) << 10) | 0x1F)))
// Generic DPP: dst = src[permuted lane], all lanes valid
#define DPPF(v, ctrl) __int_as_float(__builtin_amdgcn_update_dpp(__float_as_int(v), __float_as_int(v), (ctrl), 0xF, 0xF, false))
// quad_perm broadcast of quad-lane k
#define QB(v, k) DPPF(v, 0x55 * (k))
// Direction-free lane exchanges within a row of 16 (verified rounds 1-2-6, absmax 0):
#define XOR3(v)  DPPF(v, 0x1B)   // quad_perm [3,2,1,0]
#define XOR7(v)  DPPF(v, 0x141)  // ROW_HALF_MIRROR
#define XOR8(v)  DPPF(v, 0x128)  // ROW_ROR:8

struct X4 { float4 a, b, c, d; };   // one timestep: 16 floats, 64 B

// amdgpu_waves_per_eu(1,1): grid supplies exactly 1 wave/SIMD, so tell the
// scheduler+RA that occupancy target is 1 -> full 256-VGPR budget -> the
// 8-slot prefetch ring below actually materializes instead of being
// sunk/rematerialized to chase occupancy we can never use (R1/R2/R6: the
// compiler collapsed every pipeline to 76/84/32 VGPRs and exposed memory
// latency on the serial LSTM chain).
__global__ __launch_bounds__(256)
__attribute__((amdgpu_waves_per_eu(1, 1)))
void lstm_mlp_kernel(
    const float* __restrict__ x,   // [B,512,16]
    const float* __restrict__ Wk,  // [16,16]
    const float* __restrict__ Wr,  // [4,16]
    const float* __restrict__ bg,  // [16]
    const float* __restrict__ W1,  // [4,64]
    const float* __restrict__ b1,  // [64]
    const float* __restrict__ W2,  // [64,5]
    const float* __restrict__ b2,  // [5]
    float* __restrict__ out,       // [B,5]
    int B)
{
    const int tid = blockIdx.x * 256 + threadIdx.x;
    const int seq = tid >> 4;
    if (seq >= B) return;
    const int i16 = tid & 15;
    const int j   = i16 >> 2;   // hidden unit owned by this quad
    const int q   = i16 & 3;    // gate type: 0=i, 1=f, 2=g(tanh), 3=o
    const int gate = q * 4 + j; // column in gates[16] (Keras order i,f,g,o)

    // activation pre-scale folded into weights (verified rounds 2/6, absmax 0)
    const bool is_g = (q == 2);
    const float k1 = is_g ? (-2.0f * LOG2E) : (-LOG2E);
    const float m1c = is_g ? (-4.0f * LOG2E) : 1.0f;
    const float m0c = is_g ? (2.0f * LOG2E) : 0.0f;

    float wk[16];
#pragma unroll
    for (int f = 0; f < 16; ++f) wk[f] = k1 * Wk[f * 16 + gate];
    const float wr0 = k1 * Wr[(j ^ 0) * 16 + gate];
    const float wr1 = k1 * Wr[(j ^ 1) * 16 + gate];
    const float wr2 = k1 * Wr[(j ^ 2) * 16 + gate];
    const float wr3 = k1 * Wr[(j ^ 3) * 16 + gate];
    const float biasS = k1 * bg[gate];

    const X4* xt = reinterpret_cast<const X4*>(x) + (size_t)seq * TLEN;

    float cs = 0.0f, h = 0.0f;   // cs = -2*log2e * c

#define DOT4S(v, w0_, w1_, w2_, w3_, seed) \
    fmaf((v).x, (w0_), fmaf((v).y, (w1_), fmaf((v).z, (w2_), fmaf((v).w, (w3_), (seed)))))
#define DOTB(Bk) \
    ((DOT4S((Bk).a, wk[0], wk[1], wk[2], wk[3], biasS) + \
      DOT4S((Bk).b, wk[4], wk[5], wk[6], wk[7], 0.0f)) + \
     (DOT4S((Bk).c, wk[8], wk[9], wk[10], wk[11], 0.0f) + \
      DOT4S((Bk).d, wk[12], wk[13], wk[14], wk[15], 0.0f)))

#define STEP(XD) { \
    float h1_ = XOR7(XOR3(h));   /* h[j^1] */ \
    float h2_ = XOR8(h);         /* h[j^2] */ \
    float h3_ = XOR8(h1_);       /* h[j^3] */ \
    float pre = fmaf(h, wr0, (XD)); \
    pre = fmaf(h2_, wr2, pre); \
    pre = fmaf(h1_, wr1, pre); \
    pre = fmaf(h3_, wr3, pre); \
    float r_ = RCPF(1.0f + EXP2F(pre)); \
    float av = fmaf(m1c, r_, m0c); \
    float iv = QB(av, 0); \
    float fv = QB(av, 1); \
    float gv = QB(av, 2); \
    float ov = QB(av, 3); \
    cs = fmaf(fv, cs, iv * gv); \
    float th_ = fmaf(2.0f, RCPF(1.0f + EXP2F(cs)), -1.0f); \
    h = ov * th_; }

    // 8-deep prefetch ring: B0..B7 hold x[t..t+7]; loads issued 8 steps ahead.
    X4 B0 = xt[0], B1 = xt[1], B2 = xt[2], B3 = xt[3];
    X4 B4 = xt[4], B5 = xt[5], B6 = xt[6], B7 = xt[7];

    for (int t = 0; t < TLEN - 8; t += 8) {
        { float xd = DOTB(B0); B0 = xt[t +  8]; STEP(xd); }
        { float xd = DOTB(B1); B1 = xt[t +  9]; STEP(xd); }
        { float xd = DOTB(B2); B2 = xt[t + 10]; STEP(xd); }
        { float xd = DOTB(B3); B3 = xt[t + 11]; STEP(xd); }
        { float xd = DOTB(B4); B4 = xt[t + 12]; STEP(xd); }
        { float xd = DOTB(B5); B5 = xt[t + 13]; STEP(xd); }
        { float xd = DOTB(B6); B6 = xt[t + 14]; STEP(xd); }
        { float xd = DOTB(B7); B7 = xt[t + 15]; STEP(xd); }
    }
    // tail: t = 504..511, no prefetch
    { float xd = DOTB(B0); STEP(xd); }
    { float xd = DOTB(B1); STEP(xd); }
    { float xd = DOTB(B2); STEP(xd); }
    { float xd = DOTB(B3); STEP(xd); }
    { float xd = DOTB(B4); STEP(xd); }
    { float xd = DOTB(B5); STEP(xd); }
    { float xd = DOTB(B6); STEP(xd); }
    { float xd = DOTB(B7); STEP(xd); }

    // ---- MLP head (runs once; verified rounds 2/6) ----
    float hA = h;
    float hB = SWZ(h, 4), hC = SWZ(h, 8), hD = SWZ(h, 12);

    float p0 = 0.f, p1 = 0.f, p2 = 0.f, p3 = 0.f, p4 = 0.f;
#pragma unroll
    for (int r = 0; r < 4; ++r) {
        const int u = i16 * 4 + r;            // hidden unit of layer 1, 4 per lane
        float acc = b1[u];
        acc = fmaf(hA, W1[(j ^ 0) * 64 + u], acc);
        acc = fmaf(hB, W1[(j ^ 1) * 64 + u], acc);
        acc = fmaf(hC, W1[(j ^ 2) * 64 + u], acc);
        acc = fmaf(hD, W1[(j ^ 3) * 64 + u], acc);
        acc = fmaxf(acc, 0.0f);
        p0 = fmaf(acc, W2[u * 5 + 0], p0);
        p1 = fmaf(acc, W2[u * 5 + 1], p1);
        p2 = fmaf(acc, W2[u * 5 + 2], p2);
        p3 = fmaf(acc, W2[u * 5 + 3], p3);
        p4 = fmaf(acc, W2[u * 5 + 4], p4);
    }
    // butterfly all-reduce across the 16-lane group
    p0 += SWZ(p0, 1); p1 += SWZ(p1, 1); p2 += SWZ(p2, 1); p3 += SWZ(p3, 1); p4 += SWZ(p4, 1);
    p0 += SWZ(p0, 2); p1 += SWZ(p1, 2); p2 += SWZ(p2, 2); p3 += SWZ(p3, 2); p4 += SWZ(p4, 2);
    p0 += SWZ(p0, 4); p1 += SWZ(p1, 4); p2 += SWZ(p2, 4); p3 += SWZ(p3, 4); p4 += SWZ(p4, 4);
    p0 += SWZ(p0, 8); p1 += SWZ(p1, 8); p2 += SWZ(p2, 8); p3 += SWZ(p3, 8); p4 += SWZ(p4, 8);

    p0 += b2[0]; p1 += b2[1]; p2 += b2[2]; p3 += b2[3]; p4 += b2[4];

    float mx = fmaxf(fmaxf(fmaxf(p0, p1), fmaxf(p2, p3)), p4);
    float e0 = EXP2F((p0 - mx) * LOG2E);
    float e1 = EXP2F((p1 - mx) * LOG2E);
    float e2 = EXP2F((p2 - mx) * LOG2E);
    float e3 = EXP2F((p3 - mx) * LOG2E);
    float e4 = EXP2F((p4 - mx) * LOG2E);
    float s = ((e0 + e1) + (e2 + e3)) + e4;
    float rs = RCPF(s);

    if (i16 == 0) {
        float* op = out + (size_t)seq * 5;
        op[0] = e0 * rs; op[1] = e1 * rs; op[2] = e2 * rs;
        op[3] = e3 * rs; op[4] = e4 * rs;
    }
}

extern "C" void kernel_launch(void* const* d_in, const int* in_sizes, int n_in,
                              void* d_out, int out_size, void* d_ws, size_t ws_size,
                              hipStream_t stream) {
    const float* x  = (const float*)d_in[0];
    const float* Wk = (const float*)d_in[1];
    const float* Wr = (const float*)d_in[2];
    const float* bg = (const float*)d_in[3];
    const float* W1 = (const float*)d_in[4];
    const float* b1 = (const float*)d_in[5];
    const float* W2 = (const float*)d_in[6];
    const float* b2 = (const float*)d_in[7];
    float* out = (float*)d_out;

    const int B = in_sizes[0] / (TLEN * 16);   // 4096
    const int threads = B * 16;
    dim3 block(256);
    dim3 grid((threads + 255) / 256);
    lstm_mlp_kernel<<<grid, block, 0, stream>>>(x, Wk, Wr, bg, W1, b1, W2, b2, out, B);
}